// Round 1
// baseline (104.391 us; speedup 1.0000x reference)
//
#include <hip/hip_runtime.h>
#include <math.h>

#define NQ 4
#define DIM 16
#define K 512
#define RPB 64   // rows per block
#define RPW 16   // rows per wave

// ---------------------------------------------------------------------------
// Fused kernel: GEMM + quantum circuit + post-projection in one launch.
//
// Block = 256 threads = 4 waves; each wave computes pre-activations for 16
// batch rows (64 rows/block, 512 blocks at B=32768 -> exactly 2 blocks/CU).
// Per-wave GEMM: lanes split K=512 as 2x float4; w fragments (8 KB) are
// L1-hot.  Rows are processed with a depth-1 prefetch and an IMMEDIATE
// per-row compacting shuffle reduction (7 shuffles), so only 4 accumulators
// are ever live; lanes 0..3 deposit the row's 4 pre-activations to LDS.
// After one __syncthreads, wave 0 runs the 4-qubit register-resident
// statevector circuit with ALL 64 lanes (one row per lane) -- 4x the
// circuit-tail lane utilization of the previous 16-rows/block version.
// ---------------------------------------------------------------------------
__global__ __launch_bounds__(256) void qnet_fused(const float* __restrict__ x,
                                                  const float* __restrict__ w,
                                                  const float* __restrict__ bias,
                                                  const float* __restrict__ u3p,
                                                  const float* __restrict__ post_w,
                                                  const float* __restrict__ post_b,
                                                  float* __restrict__ out,
                                                  int B) {
    __shared__ float lds_pre[RPB * 4];   // [row_local(64)][q(4)]

    const int wave = (int)(threadIdx.x >> 6);
    const int lane = (int)(threadIdx.x & 63);
    const int block_row0 = (int)blockIdx.x * RPB;
    const int row0 = block_row0 + wave * RPW;

    // ---- GEMM phase -------------------------------------------------------
    {
        float4 wf[NQ][2];
#pragma unroll
        for (int q = 0; q < NQ; ++q) {
#pragma unroll
            for (int h = 0; h < 2; ++h)
                wf[q][h] = *(const float4*)(w + q * K + h * 256 + lane * 4);
        }

        const int l1 = lane & 1;
        const int l2 = lane & 2;

        int rc = row0; if (rc > B - 1) rc = B - 1;       // clamp (B%64==0 in practice)
        const float* xr = x + (size_t)rc * K;
        float4 xa0 = *(const float4*)(xr + lane * 4);
        float4 xa1 = *(const float4*)(xr + 256 + lane * 4);

#pragma unroll
        for (int r = 0; r < RPW; ++r) {
            float4 xb0, xb1;
            if (r + 1 < RPW) {                            // depth-1 row prefetch
                int rn = row0 + r + 1; if (rn > B - 1) rn = B - 1;
                const float* xn = x + (size_t)rn * K;
                xb0 = *(const float4*)(xn + lane * 4);
                xb1 = *(const float4*)(xn + 256 + lane * 4);
            }

            float a[NQ];
#pragma unroll
            for (int q = 0; q < NQ; ++q) {
                a[q] = xa0.x * wf[q][0].x + xa0.y * wf[q][0].y
                     + xa0.z * wf[q][0].z + xa0.w * wf[q][0].w
                     + xa1.x * wf[q][1].x + xa1.y * wf[q][1].y
                     + xa1.z * wf[q][1].z + xa1.w * wf[q][1].w;
            }

            // Compacting reduction: lane ends with the full-K sum for q=(lane&3).
            float a01k = l1 ? a[1] : a[0];
            float a01s = l1 ? a[0] : a[1];
            a01k += __shfl_xor(a01s, 1, 64);
            float a23k = l1 ? a[3] : a[2];
            float a23s = l1 ? a[2] : a[3];
            a23k += __shfl_xor(a23s, 1, 64);
            float vk = l2 ? a23k : a01k;
            float vs = l2 ? a01k : a23k;
            vk += __shfl_xor(vs, 2, 64);
#pragma unroll
            for (int off = 4; off <= 32; off <<= 1)
                vk += __shfl_xor(vk, off, 64);

            if (lane < 4)
                lds_pre[(wave * RPW + r) * 4 + lane] = vk;

            xa0 = xb0; xa1 = xb1;
        }
    }
    __syncthreads();

    // ---- Circuit phase: wave 0, one row per lane (64 rows) ----------------
    const int t = (int)threadIdx.x;
    if (t >= RPB) return;
    const int b = block_row0 + t;
    if (b >= B) return;

    const float4 pv = *(const float4*)(&lds_pre[t * 4]);
    float pre[NQ] = {pv.x + bias[0], pv.y + bias[1], pv.z + bias[2], pv.w + bias[3]};

    float ry[NQ], rz[NQ];
#pragma unroll
    for (int q = 0; q < NQ; ++q) {
        // tanh(z) = 1 - 2/(exp(2z)+1)
        float z = pre[q] * 0.1f;
        float tnh = 1.0f - 2.0f / (__expf(2.0f * z) + 1.0f);
        float qi = tnh * 1.5707963267948966f;
        ry[q] = atanf(qi);
        rz[q] = atanf(qi * qi);
    }

    // H^4 |0000> = uniform 1/4 (real).
    float sr[DIM], si[DIM];
#pragma unroll
    for (int i = 0; i < DIM; ++i) { sr[i] = 0.25f; si[i] = 0.0f; }

    // RY
#pragma unroll
    for (int q = 0; q < NQ; ++q) {
        float c, s;
        __sincosf(ry[q] * 0.5f, &s, &c);
        const int m = 1 << (3 - q);
#pragma unroll
        for (int i = 0; i < DIM; ++i) {
            if (i & m) continue;
            const int j = i | m;
            float r0 = sr[i], i0 = si[i], r1 = sr[j], i1 = si[j];
            sr[i] = c * r0 - s * r1;  si[i] = c * i0 - s * i1;
            sr[j] = s * r0 + c * r1;  si[j] = s * i0 + c * i1;
        }
    }

    // RZ
#pragma unroll
    for (int q = 0; q < NQ; ++q) {
        float c, s;
        __sincosf(rz[q] * 0.5f, &s, &c);
        const int m = 1 << (3 - q);
#pragma unroll
        for (int i = 0; i < DIM; ++i) {
            const float sg = (i & m) ? s : -s;
            float r = sr[i], im = si[i];
            sr[i] = c * r - sg * im;
            si[i] = c * im + sg * r;
        }
    }

    // CNOT ring step=1 then step=2
    const int cn_c[8] = {0, 1, 2, 3, 0, 1, 2, 3};
    const int cn_t[8] = {1, 2, 3, 0, 2, 3, 0, 1};
#pragma unroll
    for (int k = 0; k < 8; ++k) {
        const int cm = 1 << (3 - cn_c[k]);
        const int tm = 1 << (3 - cn_t[k]);
#pragma unroll
        for (int i = 0; i < DIM; ++i) {
            if ((i & cm) && !(i & tm)) {
                const int j = i | tm;
                float tr = sr[i]; sr[i] = sr[j]; sr[j] = tr;
                float ti = si[i]; si[i] = si[j]; si[j] = ti;
            }
        }
    }

    // U3
#pragma unroll
    for (int q = 0; q < NQ; ++q) {
        float th = u3p[q * 3 + 0], ph = u3p[q * 3 + 1], la = u3p[q * 3 + 2];
        float ct, st, cl, sl, cp, sp, cpl, spl;
        __sincosf(th * 0.5f, &st, &ct);
        __sincosf(la, &sl, &cl);
        __sincosf(ph, &sp, &cp);
        __sincosf(ph + la, &spl, &cpl);
        const float g01r = -cl * st, g01i = -sl * st;
        const float g10r = cp * st,  g10i = sp * st;
        const float g11r = cpl * ct, g11i = spl * ct;
        const int m = 1 << (3 - q);
#pragma unroll
        for (int i = 0; i < DIM; ++i) {
            if (i & m) continue;
            const int j = i | m;
            float r0 = sr[i], i0 = si[i], r1 = sr[j], i1 = si[j];
            sr[i] = ct * r0 + g01r * r1 - g01i * i1;
            si[i] = ct * i0 + g01r * i1 + g01i * r1;
            sr[j] = g10r * r0 - g10i * i0 + g11r * r1 - g11i * i1;
            si[j] = g10r * i0 + g10i * r0 + g11r * i1 + g11i * r1;
        }
    }

    // Z expectations + post projection
    float ex[NQ] = {0.f, 0.f, 0.f, 0.f};
#pragma unroll
    for (int i = 0; i < DIM; ++i) {
        const float p2 = sr[i] * sr[i] + si[i] * si[i];
#pragma unroll
        for (int q = 0; q < NQ; ++q)
            ex[q] += (i & (1 << (3 - q))) ? -p2 : p2;
    }

    float o0 = post_b[0], o1 = post_b[1];
#pragma unroll
    for (int q = 0; q < NQ; ++q) {
        o0 += ex[q] * post_w[q];
        o1 += ex[q] * post_w[4 + q];
    }
    *(float2*)(out + (size_t)b * 2) = make_float2(o0, o1);
}

extern "C" void kernel_launch(void* const* d_in, const int* in_sizes, int n_in,
                              void* d_out, int out_size, void* d_ws, size_t ws_size,
                              hipStream_t stream) {
    const float* x      = (const float*)d_in[0];  // [B, 512]
    const float* pre_w  = (const float*)d_in[1];  // [4, 512]
    const float* pre_b  = (const float*)d_in[2];  // [4]
    const float* u3p    = (const float*)d_in[3];  // [4, 3]
    const float* post_w = (const float*)d_in[4];  // [2, 4]
    const float* post_b = (const float*)d_in[5];  // [2]
    float* out = (float*)d_out;                   // [B, 2]

    const int B = in_sizes[0] / K;                // 32768

    const int blocks = (B + RPB - 1) / RPB;       // 512 at B=32768
    qnet_fused<<<blocks, 256, 0, stream>>>(x, pre_w, pre_b, u3p, post_w, post_b, out, B);
}